// Round 6
// baseline (405.229 us; speedup 1.0000x reference)
//
#include <hip/hip_runtime.h>
#include <math.h>

// Problem constants (fixed by the reference).
constexpr int kN  = 250000;
constexpr int kC  = 32;
constexpr int kFC = 16;
constexpr int kFN = 16;
constexpr int kV  = 64;

// ---------------------------------------------------------------------------
// Log-space fast path (transposed log-table + quadratic Gaussian form) with
// register-resident per-class scores, plus CANDIDATE-ONLY exact fallback.
//
// Fast path, per sample:
//   acc[c] = K2_c + sum_f Lq[f][idx_f][c] + sum_f (alpha_cf*x_f^2 + beta_cf*x_f)
// where Lq[f][v][c] = logf(cat_probs[c][f][v])           (128 KB, transposed)
//       alpha = -0.5*rs^2, beta = rs^2*m, rs = fl(1/s)
//       K2_c  = logf(cp_c) + sum_f [logf(1/(2*pi*s^2)) + alpha*m^2]
// Error |acc[c] - log(S_exact_c)| <= ~3e-3 for classes near the top
// (|acc| <= ~90): logf 1-ulp terms, ~80 roundings on partial sums, quadratic
// cancellation, coefficient rounding.
//
// Accept iff best >= -86 (=> exact top score is a normal fp32; every factor
// < 1 so no intermediate underflow below the final; exact rel err ~2e-6)
// AND top-2 gap >= 6e-3 (2x the error bound).
// Fallback: exact-score (reference op order, round-1-validated bit-identical)
// ONLY classes with acc[c] >= best - 1.2e-2; true winner provably passes.
// If best < -86 (deep underflow): all 32 classes exact, preserving denormal /
// all-zero-tie -> first-max reference semantics.
//
// ROUND-6 FIX: prep wrote only 256 of 512 {alpha,beta} pairs (blockDim=256,
// guard was `if (t < 512)`); classes 16-31 read 0xAA poison -> wrong argmax.
// Now a strided loop covers all 512.
// ---------------------------------------------------------------------------

// d_ws float layout:
constexpr int WS_LQ = 0;                // [16][64][32] at [(f*64+v)*32 + c]
constexpr int WS_AB = kFC * kV * kC;    // 32768: [32][16] float2 {alpha,beta}
constexpr int WS_K2 = WS_AB + 2 * kC * kFN;  // 33792: [32] K2_c
// total 33824 floats = 135,296 bytes

__global__ __launch_bounds__(256) void nbc_prep(
    const float* __restrict__ class_probs,
    const float* __restrict__ cat_probs,
    const float* __restrict__ means,
    const float* __restrict__ stds,
    float* __restrict__ ws)
{
    const float two_pi = 2.0f * (float)M_PI;
    const int b = blockIdx.x;
    if (b < 128) {
        // Transposed log-table: one element per thread.
        const int gid = b * 256 + threadIdx.x;        // 0 .. 32767
        const int c = gid >> 10;
        const int f = (gid >> 6) & 15;
        const int v = gid & 63;
        ws[WS_LQ + (((f << 6) + v) << 5) + c] = logf(cat_probs[gid]);
    } else {
        const int t = threadIdx.x;
        // ALL 512 {alpha,beta} pairs (strided: 512 > blockDim).
        for (int i = t; i < kC * kFN; i += 256) {
            const int c = i >> 4, f = i & 15;
            const float m  = means[c * kFN + f];
            const float s  = stds [c * kFN + f];
            const float rs = 1.0f / s;
            const float al = -0.5f * (rs * rs);
            const float be = (rs * rs) * m;
            reinterpret_cast<float2*>(ws + WS_AB)[i] = make_float2(al, be);
        }
        if (t < kC) {
            float k = logf(class_probs[t]);
            for (int f = 0; f < kFN; ++f) {
                const float m  = means[t * kFN + f];
                const float s  = stds [t * kFN + f];
                const float rs = 1.0f / s;
                k += logf(1.0f / (two_pi * (s * s))) + (-0.5f * (rs * rs)) * (m * m);
            }
            ws[WS_K2 + t] = k;
        }
    }
}

__global__ __launch_bounds__(256, 4) void nbc_main(
    const int*   __restrict__ X_cat,
    const float* __restrict__ X_num,
    const float* __restrict__ class_probs,
    const float* __restrict__ cat_probs,
    const float* __restrict__ means,
    const float* __restrict__ stds,
    const float* __restrict__ ws,
    int* __restrict__ out)
{
    const int n = blockIdx.x * 256 + threadIdx.x;
    if (n >= kN) return;

    // Vector-load the 16 categorical indices and 16 numeric features.
    int   idx[kFC];
    float x  [kFN];
    {
        const int4* p4 = reinterpret_cast<const int4*>(X_cat + (size_t)n * kFC);
        int4 a0 = p4[0], a1 = p4[1], a2 = p4[2], a3 = p4[3];
        idx[0]=a0.x;  idx[1]=a0.y;  idx[2]=a0.z;  idx[3]=a0.w;
        idx[4]=a1.x;  idx[5]=a1.y;  idx[6]=a1.z;  idx[7]=a1.w;
        idx[8]=a2.x;  idx[9]=a2.y;  idx[10]=a2.z; idx[11]=a2.w;
        idx[12]=a3.x; idx[13]=a3.y; idx[14]=a3.z; idx[15]=a3.w;

        const float4* q4 = reinterpret_cast<const float4*>(X_num + (size_t)n * kFN);
        float4 b0 = q4[0], b1 = q4[1], b2 = q4[2], b3 = q4[3];
        x[0]=b0.x;  x[1]=b0.y;  x[2]=b0.z;  x[3]=b0.w;
        x[4]=b1.x;  x[5]=b1.y;  x[6]=b1.z;  x[7]=b1.w;
        x[8]=b2.x;  x[9]=b2.y;  x[10]=b2.z; x[11]=b2.w;
        x[12]=b3.x; x[13]=b3.y; x[14]=b3.z; x[15]=b3.w;
    }

    const float*  __restrict__ Lq = ws + WS_LQ;
    const float2* __restrict__ AB = reinterpret_cast<const float2*>(ws + WS_AB);
    const float*  __restrict__ K2 = ws + WS_K2;

    float x2[kFN];
    #pragma unroll
    for (int f = 0; f < kFN; ++f) x2[f] = x[f] * x[f];

    // ---- fast path: all 32 class scores in registers ----
    float acc[kC];
    #pragma unroll
    for (int c = 0; c < kC; ++c) acc[c] = K2[c];      // uniform -> s_load

    // Categorical log-sums: per feature, 8 contiguous float4 covering all 32
    // classes (row is 128B-aligned). 128 independent 16B loads total.
    #pragma unroll
    for (int f = 0; f < kFC; ++f) {
        const float4* __restrict__ r =
            reinterpret_cast<const float4*>(Lq + (((f << 6) + idx[f]) << 5));
        #pragma unroll
        for (int j = 0; j < 8; ++j) {
            float4 v4 = r[j];
            acc[4*j+0] += v4.x;
            acc[4*j+1] += v4.y;
            acc[4*j+2] += v4.z;
            acc[4*j+3] += v4.w;
        }
    }

    // Gaussian quadratic form: 2 fma per (c,f); coefficients wave-uniform.
    #pragma unroll
    for (int f = 0; f < kFN; ++f) {
        #pragma unroll
        for (int c = 0; c < kC; ++c) {
            float2 ab = AB[c * kFN + f];
            acc[c] = fmaf(ab.x, x2[f], fmaf(ab.y, x[f], acc[c]));
        }
    }

    // Top-2 tracking (first-max on exact equality via strict >).
    float best = -INFINITY, second = -INFINITY;
    int   besti = 0;
    #pragma unroll
    for (int c = 0; c < kC; ++c) {
        float T = acc[c];
        if (T > best)        { second = best; best = T; besti = c; }
        else if (T > second) { second = T; }
    }

    if (best >= -86.0f && (best - second) >= 6.0e-3f) {
        out[n] = besti;
        return;
    }

    // ---- fallback: exact scoring of candidate classes only ----
    const float thr    = (best >= -86.0f) ? (best - 1.2e-2f) : -INFINITY;
    const float two_pi = 2.0f * (float)M_PI;
    float bb = -INFINITY;
    int   bi = 0;

    #pragma unroll 1
    for (int c = 0; c < kC; ++c) {
        if (acc[c] >= thr) {
            // Bit-exact categorical product (reference order, ascending f).
            const float* __restrict__ row = cat_probs + (size_t)c * (kFC * kV);
            float cat = row[idx[0]];
            #pragma unroll
            for (int f = 1; f < kFC; ++f) {
                cat *= row[(f << 6) + idx[f]];
            }
            // Exact reference numerics (round-1 validated, bit-identical).
            float num;
            #pragma unroll
            for (int f = 0; f < kFN; ++f) {
                float m = means[c * kFN + f];
                float s = stds [c * kFN + f];
                float inv = 1.0f / (two_pi * (s * s));
                float z = (x[f] - m) / s;              // IEEE divide
                float e = expf(-0.5f * (z * z));
                float lik = inv * e;
                num = (f == 0) ? lik : num * lik;
            }
            float pred = (class_probs[c] * cat) * num; // ((cp*cat)*num) like ref
            if (pred > bb) { bb = pred; bi = c; }      // strict > -> first max
        }
    }
    out[n] = bi;
}

extern "C" void kernel_launch(void* const* d_in, const int* in_sizes, int n_in,
                              void* d_out, int out_size, void* d_ws, size_t ws_size,
                              hipStream_t stream) {
    const int*   X_cat       = (const int*)  d_in[0];
    const float* X_num       = (const float*)d_in[1];
    const float* class_probs = (const float*)d_in[2];
    const float* cat_probs   = (const float*)d_in[3];
    const float* means       = (const float*)d_in[4];
    const float* stds        = (const float*)d_in[5];
    int*   out = (int*)d_out;
    float* ws  = (float*)d_ws;   // 135,296 bytes used

    // 128 blocks build the transposed log-table; block 128 builds params.
    hipLaunchKernelGGL(nbc_prep, dim3(129), dim3(256), 0, stream,
                       class_probs, cat_probs, means, stds, ws);

    dim3 block(256);
    dim3 grid((kN + 255) / 256);
    hipLaunchKernelGGL(nbc_main, grid, block, 0, stream,
                       X_cat, X_num, class_probs, cat_probs, means, stds, ws, out);
}

// Round 7
// 394.258 us; speedup vs baseline: 1.0278x; 1.0278x over previous
//
#include <hip/hip_runtime.h>
#include <math.h>

// Problem constants (fixed by the reference).
constexpr int kN  = 250000;
constexpr int kC  = 32;
constexpr int kFC = 16;
constexpr int kFN = 16;
constexpr int kV  = 64;

// ---------------------------------------------------------------------------
// Log-space fast path (transposed log-table + quadratic Gaussian form) with
// register-resident per-class scores, plus CANDIDATE-ONLY exact fallback.
//
// Fast path, per sample:
//   acc[c] = K2_c + sum_f Lq[f][idx_f][c] + sum_f (alpha_cf*x_f^2 + beta_cf*x_f)
// where Lq[f][v][c] = logf(cat_probs[c][f][v])           (128 KB, transposed)
//       alpha = -0.5*rs^2, beta = rs^2*m, rs = fl(1/s)
//       K2_c  = logf(cp_c) + sum_f [logf(1/(2*pi*s^2)) + alpha*m^2]
// Error |acc[c] - log(S_exact_c)| <= ~3e-3 for classes near the top.
//
// Accept iff best >= -86 AND top-2 gap >= 6e-3 (2x error bound).
// Fallback: exact-score (reference op order, round-1-validated bit-identical)
// ONLY candidate classes; candidates recorded in a BITMASK built with static
// acc[] indexing. ROUND-7 FIX: the previous fallback read acc[c] with a
// dynamic index inside an unroll-1 loop -> acc[] demoted to scratch ->
// ~2 GB of spill traffic (WRITE_SIZE 470 MB, VALUBusy 6%). The bitmask
// keeps every acc[] access at a compile-time index so it stays in VGPRs.
// If best < -86 (deep underflow): mask = all classes, full exact semantics
// (denormals / all-zero ties -> first max, like the reference).
// ---------------------------------------------------------------------------

// d_ws float layout:
constexpr int WS_LQ = 0;                // [16][64][32] at [(f*64+v)*32 + c]
constexpr int WS_AB = kFC * kV * kC;    // 32768: [32][16] float2 {alpha,beta}
constexpr int WS_K2 = WS_AB + 2 * kC * kFN;  // 33792: [32] K2_c
// total 33824 floats = 135,296 bytes

__global__ __launch_bounds__(256) void nbc_prep(
    const float* __restrict__ class_probs,
    const float* __restrict__ cat_probs,
    const float* __restrict__ means,
    const float* __restrict__ stds,
    float* __restrict__ ws)
{
    const float two_pi = 2.0f * (float)M_PI;
    const int b = blockIdx.x;
    if (b < 128) {
        // Transposed log-table: one element per thread.
        const int gid = b * 256 + threadIdx.x;        // 0 .. 32767
        const int c = gid >> 10;
        const int f = (gid >> 6) & 15;
        const int v = gid & 63;
        ws[WS_LQ + (((f << 6) + v) << 5) + c] = logf(cat_probs[gid]);
    } else {
        const int t = threadIdx.x;
        // ALL 512 {alpha,beta} pairs (strided: 512 > blockDim).
        for (int i = t; i < kC * kFN; i += 256) {
            const int c = i >> 4, f = i & 15;
            const float m  = means[c * kFN + f];
            const float s  = stds [c * kFN + f];
            const float rs = 1.0f / s;
            const float al = -0.5f * (rs * rs);
            const float be = (rs * rs) * m;
            reinterpret_cast<float2*>(ws + WS_AB)[i] = make_float2(al, be);
        }
        if (t < kC) {
            float k = logf(class_probs[t]);
            for (int f = 0; f < kFN; ++f) {
                const float m  = means[t * kFN + f];
                const float s  = stds [t * kFN + f];
                const float rs = 1.0f / s;
                k += logf(1.0f / (two_pi * (s * s))) + (-0.5f * (rs * rs)) * (m * m);
            }
            ws[WS_K2 + t] = k;
        }
    }
}

__global__ __launch_bounds__(256, 4) void nbc_main(
    const int*   __restrict__ X_cat,
    const float* __restrict__ X_num,
    const float* __restrict__ class_probs,
    const float* __restrict__ cat_probs,
    const float* __restrict__ means,
    const float* __restrict__ stds,
    const float* __restrict__ ws,
    int* __restrict__ out)
{
    const int n = blockIdx.x * 256 + threadIdx.x;
    if (n >= kN) return;

    // Vector-load the 16 categorical indices and 16 numeric features.
    int   idx[kFC];
    float x  [kFN];
    {
        const int4* p4 = reinterpret_cast<const int4*>(X_cat + (size_t)n * kFC);
        int4 a0 = p4[0], a1 = p4[1], a2 = p4[2], a3 = p4[3];
        idx[0]=a0.x;  idx[1]=a0.y;  idx[2]=a0.z;  idx[3]=a0.w;
        idx[4]=a1.x;  idx[5]=a1.y;  idx[6]=a1.z;  idx[7]=a1.w;
        idx[8]=a2.x;  idx[9]=a2.y;  idx[10]=a2.z; idx[11]=a2.w;
        idx[12]=a3.x; idx[13]=a3.y; idx[14]=a3.z; idx[15]=a3.w;

        const float4* q4 = reinterpret_cast<const float4*>(X_num + (size_t)n * kFN);
        float4 b0 = q4[0], b1 = q4[1], b2 = q4[2], b3 = q4[3];
        x[0]=b0.x;  x[1]=b0.y;  x[2]=b0.z;  x[3]=b0.w;
        x[4]=b1.x;  x[5]=b1.y;  x[6]=b1.z;  x[7]=b1.w;
        x[8]=b2.x;  x[9]=b2.y;  x[10]=b2.z; x[11]=b2.w;
        x[12]=b3.x; x[13]=b3.y; x[14]=b3.z; x[15]=b3.w;
    }

    const float*  __restrict__ Lq = ws + WS_LQ;
    const float2* __restrict__ AB = reinterpret_cast<const float2*>(ws + WS_AB);
    const float*  __restrict__ K2 = ws + WS_K2;

    float x2[kFN];
    #pragma unroll
    for (int f = 0; f < kFN; ++f) x2[f] = x[f] * x[f];

    // ---- fast path: all 32 class scores in registers ----
    float acc[kC];
    #pragma unroll
    for (int c = 0; c < kC; ++c) acc[c] = K2[c];      // uniform -> s_load

    // Categorical log-sums: per feature, 8 contiguous float4 covering all 32
    // classes (row is 128B-aligned). 128 independent 16B loads total.
    #pragma unroll
    for (int f = 0; f < kFC; ++f) {
        const float4* __restrict__ r =
            reinterpret_cast<const float4*>(Lq + (((f << 6) + idx[f]) << 5));
        #pragma unroll
        for (int j = 0; j < 8; ++j) {
            float4 v4 = r[j];
            acc[4*j+0] += v4.x;
            acc[4*j+1] += v4.y;
            acc[4*j+2] += v4.z;
            acc[4*j+3] += v4.w;
        }
    }

    // Gaussian quadratic form: 2 fma per (c,f); coefficients wave-uniform.
    #pragma unroll
    for (int f = 0; f < kFN; ++f) {
        #pragma unroll
        for (int c = 0; c < kC; ++c) {
            float2 ab = AB[c * kFN + f];
            acc[c] = fmaf(ab.x, x2[f], fmaf(ab.y, x[f], acc[c]));
        }
    }

    // Top-2 tracking (first-max on exact equality via strict >).
    float best = -INFINITY, second = -INFINITY;
    int   besti = 0;
    #pragma unroll
    for (int c = 0; c < kC; ++c) {
        float T = acc[c];
        if (T > best)        { second = best; best = T; besti = c; }
        else if (T > second) { second = T; }
    }

    if (best >= -86.0f && (best - second) >= 6.0e-3f) {
        out[n] = besti;
        return;
    }

    // Candidate bitmask — STATIC acc[] indexing only (keeps acc in VGPRs).
    const float thr = (best >= -86.0f) ? (best - 1.2e-2f) : -INFINITY;
    unsigned int mask = 0u;
    #pragma unroll
    for (int c = 0; c < kC; ++c) {
        mask |= (acc[c] >= thr) ? (1u << c) : 0u;
    }

    // ---- fallback: exact scoring of candidate classes only ----
    const float two_pi = 2.0f * (float)M_PI;
    float bb = -INFINITY;
    int   bi = 0;

    #pragma unroll 1
    for (int c = 0; c < kC; ++c) {
        if ((mask >> c) & 1u) {
            // Bit-exact categorical product (reference order, ascending f).
            const float* __restrict__ row = cat_probs + (size_t)c * (kFC * kV);
            float cat = row[idx[0]];
            #pragma unroll
            for (int f = 1; f < kFC; ++f) {
                cat *= row[(f << 6) + idx[f]];
            }
            // Exact reference numerics (round-1 validated, bit-identical).
            float num;
            #pragma unroll
            for (int f = 0; f < kFN; ++f) {
                float m = means[c * kFN + f];
                float s = stds [c * kFN + f];
                float inv = 1.0f / (two_pi * (s * s));
                float z = (x[f] - m) / s;              // IEEE divide
                float e = expf(-0.5f * (z * z));
                float lik = inv * e;
                num = (f == 0) ? lik : num * lik;
            }
            float pred = (class_probs[c] * cat) * num; // ((cp*cat)*num) like ref
            if (pred > bb) { bb = pred; bi = c; }      // strict > -> first max
        }
    }
    out[n] = bi;
}

extern "C" void kernel_launch(void* const* d_in, const int* in_sizes, int n_in,
                              void* d_out, int out_size, void* d_ws, size_t ws_size,
                              hipStream_t stream) {
    const int*   X_cat       = (const int*)  d_in[0];
    const float* X_num       = (const float*)d_in[1];
    const float* class_probs = (const float*)d_in[2];
    const float* cat_probs   = (const float*)d_in[3];
    const float* means       = (const float*)d_in[4];
    const float* stds        = (const float*)d_in[5];
    int*   out = (int*)d_out;
    float* ws  = (float*)d_ws;   // 135,296 bytes used

    // 128 blocks build the transposed log-table; block 128 builds params.
    hipLaunchKernelGGL(nbc_prep, dim3(129), dim3(256), 0, stream,
                       class_probs, cat_probs, means, stds, ws);

    dim3 block(256);
    dim3 grid((kN + 255) / 256);
    hipLaunchKernelGGL(nbc_main, grid, block, 0, stream,
                       X_cat, X_num, class_probs, cat_probs, means, stds, ws, out);
}